// Round 1
// 144.548 us; speedup vs baseline: 1.0107x; 1.0107x over previous
//
#include <hip/hip_runtime.h>
#include <stdint.h>

// Kalman filter scan: B=128, T=256, V=256. One thread per (b,v) track.
// Decoupled-axes algebra (R2): one shared 2x2 Riccati recursion (p00,p01,p11),
// scalar innovation variance, both axes share gain K. ~20 VALU instr/step.
//
// R6/R7 lesson: loop-carried asm-load buffers create PHIs; the allocator may
// insert v_mov copies on the backedge that read the dest of an IN-FLIGHT
// global_load -> junk -> NaN. Previous round's mitigation (body-local buffers,
// drain to vmcnt(0) every 16 steps) is correct but pays ~900 cyc HBM latency
// at 16 seams (~6 us/wave) and lets the VMEM queue collapse to 0 every body.
//
// THIS ROUND: fully straight-line software pipeline -- NO backedges exist, so
// no PHIs are possible and the queue never drains until the epilogue:
//   * 8 named group buffers b0..b7 (4 steps each; 32 f4 = 128 VGPRs)
//   * prologue issues 8 groups (32 dwordx4 in flight = 32 KB/wave)
//   * steady state (56 groups): wait vmcnt(28) -> oldest group landed,
//     consume its 4 steps, immediately re-issue that buffer. 7 groups of
//     compute (~1120 cyc) sit between any group's issue and its wait, so
//     ~900 cyc HBM latency is fully hidden and >=28 loads stay outstanding.
//   * epilogue drains 28 -> 24 -> ... -> 0 with literal vmcnt immediates.
//   * __launch_bounds__(64,1): lifts the 8-wave VGPR budget; ~160 live VGPRs.

#define KF_B 128
#define KF_T 256
#define KF_V 256

typedef float f4 __attribute__((ext_vector_type(4)));

// one dwordx4: dst <- mem[sbase + voff + imm]
#define GLOAD(dst, sbase, imm)                                         \
    asm volatile("global_load_dwordx4 %0, %1, %2 offset:" #imm         \
                 : "=v"(dst) : "v"(voff), "s"(sbase) : "memory")

// wait until at most N VMEM outstanding; tie regs so uses depend on it
#define WAITVM(N, B)                                                   \
    asm volatile("s_waitcnt vmcnt(" #N ")"                             \
                 : "+v"((B)[0]), "+v"((B)[1]),                         \
                   "+v"((B)[2]), "+v"((B)[3]) :: "memory")

// issue one group's 4 loads (k=0..2 normal; k=3 shifted -4B so the dwordx4
// never reads past the end of the input buffer; t>=3 so never before start)
#define KF_ISSUE(buf)                          \
    do {                                       \
        GLOAD((buf)[0], sb0, 0);               \
        GLOAD((buf)[1], sb0, 3072);            \
        GLOAD((buf)[2], sb1, 0);               \
        GLOAD((buf)[3], sb1, 3068);            \
        sb0 += 12288; sb1 += 12288;            \
    } while (0)

#define KF_STEP3(label, z0, z1)                                         \
    do {                                                                \
        /* predict */                                                   \
        const float xp0 = x0 + v0;                                      \
        const float xp1 = x1 + v1;                                      \
        const float q00 = p00 + 2.f * p01 + p11 + 0.01f;                \
        const float q01 = p01 + p11;                                    \
        const float q11 = p11 + 0.01f;                                  \
        /* scalar innovation variance + masked inverse */               \
        const float S = q00 + 1.f;                                      \
        const float m = ((label) != -1.0f) ? 1.0f : 0.0f;               \
        const float is = m * __builtin_amdgcn_rcpf(S);                  \
        const float K0 = q00 * is;                                      \
        const float K1 = q01 * is;                                      \
        /* state update, both axes share K */                           \
        const float y0 = (z0) - xp0;                                    \
        const float y1 = (z1) - xp1;                                    \
        x0 = xp0 + K0 * y0;                                             \
        v0 = v0 + K1 * y0;                                              \
        x1 = xp1 + K0 * y1;                                             \
        v1 = v1 + K1 * y1;                                              \
        /* covariance update */                                         \
        p00 = q00 - K0 * q00;                                           \
        p01 = q01 - K0 * q01;                                           \
        p11 = q11 - K1 * q01;                                           \
    } while (0)

// consume 4 steps; k=3 came from the shifted load -> components [1],[2],[3]
#define KF_CONSUME(B)                                        \
    do {                                                     \
        KF_STEP3((B)[0][0], (B)[0][1], (B)[0][2]);           \
        KF_STEP3((B)[1][0], (B)[1][1], (B)[1][2]);           \
        KF_STEP3((B)[2][0], (B)[2][1], (B)[2][2]);           \
        KF_STEP3((B)[3][1], (B)[3][2], (B)[3][3]);           \
    } while (0)

// steady-state cell: oldest group landed (28 = 32 - 4 outstanding),
// consume it, refill the same buffer with the group 8 ahead.
#define KF_STEADY(B)  do { WAITVM(28, B); KF_CONSUME(B); KF_ISSUE(B); } while (0)
#define KF_STEADY8()                                          \
    do {                                                      \
        KF_STEADY(b0); KF_STEADY(b1); KF_STEADY(b2);          \
        KF_STEADY(b3); KF_STEADY(b4); KF_STEADY(b5);          \
        KF_STEADY(b6); KF_STEADY(b7);                         \
    } while (0)

__global__ __launch_bounds__(64, 1) void kf_kernel(const float* __restrict__ batch,
                                                   float* __restrict__ out) {
    // b uniform from blockIdx only (provably scalar); v per-lane.
    const int blk = blockIdx.x;
    const int b = blk >> 2;                              // 0..127, SGPR
    const int v = ((blk & 3) << 6) | threadIdx.x;        // 0..255, VGPR

    // SADDR+voffset addressing: uniform scalar bases, per-lane byte offset
    const uint32_t voff = (uint32_t)v * 12u;
    uint64_t sb0 = (uint64_t)batch + (uint64_t)b * (KF_T * KF_V * 3 * 4);
    uint64_t sb1 = sb0 + 6144;   // covers k=2 (off 0) and k=3 (off 3068)

    // shared 2x2 covariance (both axes identical), per-axis states
    float p00 = 1000.f, p01 = 0.f, p11 = 1000.f;
    float x0 = 0.f, v0 = 0.f;
    float x1 = 0.f, v1 = 0.f;

    // 64 groups x 4 steps, straight-line. 8 rotating buffers, no backedges.
    f4 b0[4], b1[4], b2[4], b3[4], b4[4], b5[4], b6[4], b7[4];

    // ---- prologue: fill the pipe (32 loads in flight) ----
    KF_ISSUE(b0); KF_ISSUE(b1); KF_ISSUE(b2); KF_ISSUE(b3);
    KF_ISSUE(b4); KF_ISSUE(b5); KF_ISSUE(b6); KF_ISSUE(b7);

    // ---- steady state: 7 x 8 = 56 groups ----
    KF_STEADY8();   // groups  0.. 7 consumed, 16..23 issued
    KF_STEADY8();   // groups  8..15 consumed, 24..31 issued
    KF_STEADY8();
    KF_STEADY8();
    KF_STEADY8();
    KF_STEADY8();
    KF_STEADY8();   // groups 48..55 consumed, 56..63 issued

    // ---- epilogue: drain groups 56..63, vmcnt 28 -> 0 ----
    WAITVM(28, b0); KF_CONSUME(b0);
    WAITVM(24, b1); KF_CONSUME(b1);
    WAITVM(20, b2); KF_CONSUME(b2);
    WAITVM(16, b3); KF_CONSUME(b3);
    WAITVM(12, b4); KF_CONSUME(b4);
    WAITVM(8,  b5); KF_CONSUME(b5);
    WAITVM(4,  b6); KF_CONSUME(b6);
    WAITVM(0,  b7); KF_CONSUME(b7);

    // ---- output: (1, x, y) per track ----
    const int tid = blk * 64 + threadIdx.x;
    float* o = out + (size_t)tid * 3;
    o[0] = 1.0f;
    o[1] = x0;
    o[2] = x1;
}

extern "C" void kernel_launch(void* const* d_in, const int* in_sizes, int n_in,
                              void* d_out, int out_size, void* d_ws, size_t ws_size,
                              hipStream_t stream) {
    (void)in_sizes; (void)n_in; (void)d_ws; (void)ws_size; (void)out_size;
    const float* batch = (const float*)d_in[0];
    float* out = (float*)d_out;
    const int total = KF_B * KF_V;            // 32768 threads, 512 waves
    kf_kernel<<<total / 64, 64, 0, stream>>>(batch, out);
}